// Round 16
// baseline (299.520 us; speedup 1.0000x reference)
//
#include <hip/hip_runtime.h>
#include <hip/hip_cooperative_groups.h>
#include <math.h>

namespace cg = cooperative_groups;

// Dims: B=16, H=64, W=64, Cin=3, F=32, K=3
// Primary: SINGLE cooperative kernel, 512 blocks x 256 thr (2 blocks/CU
// co-residency -- VGPR budget 256, no spill risk). Phases via grid.sync():
//   P0 prep + conv0 (2 units/block) | P1 conv1 (2 units/wave) |
//   P2 conv2+pool (2 units/wave) | P3 conv3 (waves 0-1) |
//   P4 conv4+pool+dense (waves 0-1) + counter/lastflag softmax.
// fhalf == wid&1 at every phase -> weight A-frags+bias loaded ONCE into regs.
// Image = wb>>5 at every phase -> XCD-affinity chain (2 images/XCD, L2-local).
// Fallback: if hipLaunchCooperativeKernel errors, run the proven R13
// 5-kernel pipeline (same workspace layout, same math).

typedef __attribute__((ext_vector_type(8))) short bf16x8;
typedef __attribute__((ext_vector_type(4))) float f32x4;

__device__ __align__(16) unsigned short g_wbf[32 * 288];  // bf16 [f][tap*32+pos]
__device__ __align__(64) float g_zerof[16];               // zero page (floats)

// ---- workspace layout (ushort elems) ----
#define A64e ((size_t)0)
#define B64e ((size_t)(16 * 66 * 66 * 32))            // 2,230,272
#define A32e ((size_t)(2 * 16 * 66 * 66 * 32))        // 4,460,544
#define B32e (A32e + (size_t)(16 * 34 * 34 * 32))     // 5,052,416
#define Dne  (B32e + (size_t)(16 * 34 * 34 * 32))     // Wd2 bf16 [8192][16]
#define LGe  (Dne + (size_t)131072)                   // logits f32[160] + cnt

__device__ __forceinline__ unsigned short f2bf(float x) {
  union { float f; unsigned u; } v;
  v.f = x;
  return (unsigned short)((v.u + 0x7FFFu + ((v.u >> 16) & 1u)) >> 16);
}
__device__ __forceinline__ float bf2f(unsigned short x) {
  union { unsigned u; float f; } v;
  v.u = ((unsigned)x) << 16;
  return v.f;
}
__device__ __forceinline__ int swz_bid(int bid, int nwg) {
  return (bid & 7) * (nwg >> 3) + (bid >> 3);
}

// ---- prep item dispatcher (shared by meganet P0 and fallback prep) ----
__device__ __forceinline__ void prep_item(
    int i, const float* __restrict__ wsh, const float* __restrict__ Wd,
    unsigned short* __restrict__ ws) {
  if (i < 1152) {  // g_wbf convert+permute: one 16B chunk per thread
    const int o0 = i * 8;
    const int f = o0 / 288;
    const int rem = o0 - f * 288;
    const int tap = rem >> 5;
    const int gg = (rem & 31) >> 3;
    unsigned short u[8];
#pragma unroll
    for (int j = 0; j < 8; ++j) {
      const int c = (j < 4) ? 4 * gg + j : 16 + 4 * gg + (j - 4);
      u[j] = f2bf(wsh[f * 288 + tap * 32 + c]);
    }
    uint4 o;
    o.x = u[0] | ((unsigned)u[1] << 16);
    o.y = u[2] | ((unsigned)u[3] << 16);
    o.z = u[4] | ((unsigned)u[5] << 16);
    o.w = u[6] | ((unsigned)u[7] << 16);
    *(uint4*)(g_wbf + o0) = o;
    return;
  }
  i -= 1152;
  if (i < 12544) {  // pad zeroing (one 64B chunk each)
    size_t off;
    if (i < 8320) {
      const size_t base = (i < 4160) ? A64e : B64e;
      if (i >= 4160) i -= 4160;
      if (i < 2112) {
        const int b = i / 132, rem = i - b * 132;
        const int rs = rem / 66, ch = rem - rs * 66;
        off = base + (size_t)((b * 66 + (rs ? 65 : 0)) * 66) * 32 + ch * 32;
      } else {
        i -= 2112;
        const int b = i >> 7, rem = i & 127;
        const int r = rem >> 1, side = rem & 1;
        off = base + (size_t)((b * 66 + 1 + r) * 66 + (side ? 65 : 0)) * 32;
      }
    } else {
      i -= 8320;
      const size_t base = (i < 2112) ? A32e : B32e;
      if (i >= 2112) i -= 2112;
      if (i < 1088) {
        const int b = i / 68, rem = i - b * 68;
        const int rs = rem / 34, ch = rem - rs * 34;
        off = base + (size_t)((b * 34 + (rs ? 33 : 0)) * 34) * 32 + ch * 32;
      } else {
        i -= 1088;
        const int b = i >> 6, rem = i & 63;
        const int r = rem >> 1, side = rem & 1;
        off = base + (size_t)((b * 34 + 1 + r) * 34 + (side ? 33 : 0)) * 32;
      }
    }
    uint4* p = (uint4*)(ws + off);
    const uint4 z = {0u, 0u, 0u, 0u};
    p[0] = z; p[1] = z; p[2] = z; p[3] = z;
    return;
  }
  i -= 12544;
  if (i < 8192) {  // Wd2 [8192][16] bf16, coalesced row transpose
    const int q = i;
    unsigned short u[10];
#pragma unroll
    for (int j = 0; j < 10; ++j) u[j] = f2bf(Wd[(size_t)q * 10 + j]);
    uint4 o0, o1;
    o0.x = u[0] | ((unsigned)u[1] << 16);
    o0.y = u[2] | ((unsigned)u[3] << 16);
    o0.z = u[4] | ((unsigned)u[5] << 16);
    o0.w = u[6] | ((unsigned)u[7] << 16);
    o1.x = u[8] | ((unsigned)u[9] << 16);
    o1.y = 0u; o1.z = 0u; o1.w = 0u;
    *(uint4*)(ws + Dne + (size_t)q * 16) = o0;
    *(uint4*)(ws + Dne + (size_t)q * 16 + 8) = o1;
    return;
  }
  i -= 8192;
  if (i < 161) ((unsigned*)(ws + LGe))[i] = 0u;  // logits[160] + counter
}

// ---- conv0 unit: virtual block v in [0,1024), 256 threads ----
__device__ __forceinline__ void conv0_unit(
    int v, int tid, const float* __restrict__ in, const float* __restrict__ W0,
    const float* __restrict__ b0, unsigned short* __restrict__ A64) {
  const int fg = v & 3;
  const int p = (v >> 2) * 256 + tid;
  const int b = p >> 12, rem = p & 4095, h = rem >> 6, w = rem & 63;

  const float* pt[3][3];
#pragma unroll
  for (int r = 0; r < 3; ++r) {
    const int hh = h - 1 + r;
#pragma unroll
    for (int j = 0; j < 3; ++j) {
      const int col = w - 1 + j;
      const bool ok = ((unsigned)hh < 64u) && ((unsigned)col < 64u);
      pt[r][j] = ok ? in + (((b << 6) + hh) * 64 + col) * 3 : g_zerof;
    }
  }

  float acc[8];
#pragma unroll
  for (int f = 0; f < 8; ++f) acc[f] = b0[fg * 8 + f];

#pragma unroll
  for (int dy = 0; dy < 3; ++dy)
#pragma unroll
    for (int dx = 0; dx < 3; ++dx) {
      const float c0 = pt[dy][dx][0];
      const float c1 = pt[dy][dx][1];
      const float c2 = pt[dy][dx][2];
      const float* wp = W0 + ((dy * 3 + dx) * 3) * 32 + fg * 8;
#pragma unroll
      for (int f = 0; f < 8; ++f)
        acc[f] += c0 * wp[f] + c1 * wp[32 + f] + c2 * wp[64 + f];
    }

  unsigned short* op = A64 + ((size_t)(b * 66 + 1 + h) * 66 + 1 + w) * 32;
  const int hi = fg >> 1;
#pragma unroll
  for (int q = 0; q < 2; ++q) {
    const int pos = 8 * (2 * (fg & 1) + q) + 4 * hi;
    unsigned short u0 = f2bf(fmaxf(acc[4 * q + 0], 0.f));
    unsigned short u1 = f2bf(fmaxf(acc[4 * q + 1], 0.f));
    unsigned short u2 = f2bf(fmaxf(acc[4 * q + 2], 0.f));
    unsigned short u3 = f2bf(fmaxf(acc[4 * q + 3], 0.f));
    uint2 o;
    o.x = u0 | ((unsigned)u1 << 16);
    o.y = u2 | ((unsigned)u3 << 16);
    *(uint2*)(op + pos) = o;
  }
}

// ---- conv body (B-frag load + 18 MFMA + epilogue); af/bv preloaded ----
template <int LGS, bool POOL, bool OPAD>
__device__ __forceinline__ void conv_body(
    int id, int n, int g, const unsigned short* __restrict__ act,
    unsigned short* __restrict__ outp, const bf16x8 (&af)[9],
    const float (&bv)[4]) {
  constexpr int S = 1 << LGS, PS = S + 2, LGTC = LGS - 4, TC = S >> 4;
  const int fhalf = id & 1;
  const int tc = (id >> 1) & (TC - 1);
  const int h2 = (id >> (1 + LGTC)) & ((S >> 1) - 1);
  const int b = id >> (LGS + LGTC);

  const unsigned short* pB =
      act + ((size_t)(b * PS + 2 * h2) * PS + tc * 16 + n) * 32 + 8 * g;
  bf16x8 bfr[4][3];
#pragma unroll
  for (int rr = 0; rr < 4; ++rr)
#pragma unroll
    for (int dx = 0; dx < 3; ++dx)
      bfr[rr][dx] = *(const bf16x8*)(pB + (rr * PS + dx) * 32);

  f32x4 acc0 = {0.f, 0.f, 0.f, 0.f};
  f32x4 acc1 = {0.f, 0.f, 0.f, 0.f};
#pragma unroll
  for (int tap = 0; tap < 9; ++tap) {
    const int dy = tap / 3, dx = tap - dy * 3;
    acc0 = __builtin_amdgcn_mfma_f32_16x16x32_bf16(af[tap], bfr[dy][dx], acc0, 0, 0, 0);
    acc1 = __builtin_amdgcn_mfma_f32_16x16x32_bf16(af[tap], bfr[dy + 1][dx], acc1, 0, 0, 0);
  }

  const int opos = 8 * g + 4 * fhalf;
  if (!POOL) {
#pragma unroll
    for (int t = 0; t < 2; ++t) {
      unsigned short u[4];
#pragma unroll
      for (int r = 0; r < 4; ++r) {
        const float a = (t == 0) ? acc0[r] : acc1[r];
        u[r] = f2bf(fmaxf(a + bv[r], 0.f));
      }
      uint2 o;
      o.x = u[0] | ((unsigned)u[1] << 16);
      o.y = u[2] | ((unsigned)u[3] << 16);
      unsigned short* op = outp +
          ((size_t)(b * PS + 2 * h2 + 1 + t) * PS + 1 + tc * 16 + n) * 32 + opos;
      *(uint2*)op = o;
    }
  } else {
    float m[4];
#pragma unroll
    for (int r = 0; r < 4; ++r) {
      const float v0 = fmaxf(acc0[r] + bv[r], 0.f);
      const float v1 = fmaxf(acc1[r] + bv[r], 0.f);
      m[r] = fmaxf(v0, v1);
      m[r] = fmaxf(m[r], __shfl_xor(m[r], 1, 64));
    }
    if (!(n & 1)) {
      unsigned short u[4];
#pragma unroll
      for (int r = 0; r < 4; ++r) u[r] = f2bf(m[r]);
      uint2 o;
      o.x = u[0] | ((unsigned)u[1] << 16);
      o.y = u[2] | ((unsigned)u[3] << 16);
      unsigned short* op =
          outp + ((size_t)(b * 34 + 1 + h2) * 34 + 1 + tc * 8 + (n >> 1)) * 32 + opos;
      *(uint2*)op = o;
    }
  }
}

// ==================== primary: cooperative meganet (512 blocks) =============
__global__ __launch_bounds__(256, 2) void meganet512(
    const float* __restrict__ in, const float* __restrict__ W0,
    const float* __restrict__ b0, const float* __restrict__ wsh,
    const float* __restrict__ Wd, const float* __restrict__ bsh,
    const float* __restrict__ bd, unsigned short* __restrict__ ws,
    float* __restrict__ out) {
  cg::grid_group grid = cg::this_grid();

  __shared__ float red[4][10];
  __shared__ float sm[160];
  __shared__ int lastflag;

  const int bid = (int)blockIdx.x;
  const int tid = (int)threadIdx.x;
  const int wb = swz_bid(bid, 512);  // [0,512), contiguous chunk per XCD
  const int wid = __builtin_amdgcn_readfirstlane(tid >> 6);
  const int l = tid & 63;
  const int n = l & 15, g = l >> 4;

  unsigned short* A64 = ws + A64e;
  unsigned short* B64 = ws + B64e;
  unsigned short* A32 = ws + A32e;
  unsigned short* B32 = ws + B32e;
  unsigned short* Wd2 = ws + Dne;
  float* logits = (float*)(ws + LGe);
  int* cnt = (int*)(logits + 160);

  // ---- P0: prep + conv0 (2 virtual blocks per block) ----
  prep_item(bid * 256 + tid, wsh, Wd, ws);
#pragma unroll
  for (int u = 0; u < 2; ++u) conv0_unit(wb * 2 + u, tid, in, W0, b0, A64);
  grid.sync();

  // ---- weight A-frags + bias ONCE; fhalf == wid&1 in every phase ----
  const int fh = wid & 1;
  const unsigned short* pA = g_wbf + (fh * 16 + n) * 288 + 8 * g;
  bf16x8 af[9];
#pragma unroll
  for (int t = 0; t < 9; ++t) af[t] = *(const bf16x8*)(pA + t * 32);
  const float4 bias = *(const float4*)(bsh + fh * 16 + 4 * g);
  const float bv[4] = {bias.x, bias.y, bias.z, bias.w};

  // ---- P1: conv1 (64x64), 2 units/wave; unit = 8wb+4u+wid (fhalf=wid&1) ----
#pragma unroll
  for (int u = 0; u < 2; ++u)
    conv_body<6, false, false>(wb * 8 + u * 4 + wid, n, g, A64, B64, af, bv);
  grid.sync();

  // ---- P2: conv2 + pool ----
#pragma unroll
  for (int u = 0; u < 2; ++u)
    conv_body<6, true, true>(wb * 8 + u * 4 + wid, n, g, B64, A32, af, bv);
  grid.sync();

  // ---- P3: conv3 (32x32), waves 0-1; unit = 2wb+wid (fhalf=wid) ----
  if (wid < 2) conv_body<5, false, false>(wb * 2 + wid, n, g, A32, B32, af, bv);
  grid.sync();

  // ---- P4: conv4 + pool + dense partial + softmax ----
  {
    const int bimg = wb >> 5;  // block-uniform image id
    float dacc[10];
#pragma unroll
    for (int j = 0; j < 10; ++j) dacc[j] = 0.f;

    if (wid < 2) {
      constexpr int PS = 34;
      const int id = wb * 2 + wid;
      const int fhalf = id & 1;  // == wid
      const int tc = (id >> 1) & 1;
      const int h2 = (id >> 2) & 15;

      const unsigned short* pB =
          B32 + ((size_t)(bimg * PS + 2 * h2) * PS + tc * 16 + n) * 32 + 8 * g;
      bf16x8 bfr[4][3];
#pragma unroll
      for (int rr = 0; rr < 4; ++rr)
#pragma unroll
        for (int dx = 0; dx < 3; ++dx)
          bfr[rr][dx] = *(const bf16x8*)(pB + (rr * PS + dx) * 32);

      f32x4 acc0 = {0.f, 0.f, 0.f, 0.f};
      f32x4 acc1 = {0.f, 0.f, 0.f, 0.f};
#pragma unroll
      for (int tap = 0; tap < 9; ++tap) {
        const int dy = tap / 3, dx = tap - dy * 3;
        acc0 = __builtin_amdgcn_mfma_f32_16x16x32_bf16(af[tap], bfr[dy][dx], acc0, 0, 0, 0);
        acc1 = __builtin_amdgcn_mfma_f32_16x16x32_bf16(af[tap], bfr[dy + 1][dx], acc1, 0, 0, 0);
      }

      float m[4];
#pragma unroll
      for (int r = 0; r < 4; ++r) {
        const float v0 = fmaxf(acc0[r] + bv[r], 0.f);
        const float v1 = fmaxf(acc1[r] + bv[r], 0.f);
        m[r] = fmaxf(v0, v1);
        m[r] = fmaxf(m[r], __shfl_xor(m[r], 1, 64));
      }

      if (!(n & 1)) {
        const int flat0 =
            ((h2 * 16) + tc * 8 + (n >> 1)) * 32 + fhalf * 16 + 4 * g;
        const unsigned short* wr0 = Wd2 + (size_t)flat0 * 16;
#pragma unroll
        for (int r = 0; r < 4; ++r) {
          const unsigned short* wr = wr0 + r * 16;
          const bf16x8 w0 = *(const bf16x8*)wr;
          const unsigned w1 = *(const unsigned*)(wr + 8);
          const float xv = m[r];
#pragma unroll
          for (int j = 0; j < 8; ++j) dacc[j] += xv * bf2f((unsigned short)w0[j]);
          dacc[8] += xv * bf2f((unsigned short)(w1 & 0xffffu));
          dacc[9] += xv * bf2f((unsigned short)(w1 >> 16));
        }
      }
    }
#pragma unroll
    for (int off = 32; off > 0; off >>= 1)
#pragma unroll
      for (int j = 0; j < 10; ++j) dacc[j] += __shfl_xor(dacc[j], off, 64);

    if (l == 0) {
#pragma unroll
      for (int j = 0; j < 10; ++j) red[wid][j] = dacc[j];
    }
    __syncthreads();
    if (tid < 10) {
      const float s = red[0][tid] + red[1][tid] + red[2][tid] + red[3][tid];
      atomicAdd(logits + bimg * 10 + tid, s);
      __threadfence();
    }
    __syncthreads();
    if (tid == 0) {
      const int old = atomicAdd(cnt, 1);
      lastflag = (old == 511) ? 1 : 0;
    }
    __syncthreads();

    if (lastflag) {
      if (tid < 160) {
        const int j = tid - (tid / 10) * 10;
        sm[tid] = atomicAdd(logits + tid, 0.f) + bd[j];
      }
      __syncthreads();
      if (tid < 16) {
        float lg[10];
        float mx = -1e30f;
#pragma unroll
        for (int j = 0; j < 10; ++j) {
          lg[j] = sm[tid * 10 + j];
          mx = fmaxf(mx, lg[j]);
        }
        float s = 0.f;
#pragma unroll
        for (int j = 0; j < 10; ++j) {
          lg[j] = expf(lg[j] - mx);
          s += lg[j];
        }
        const float inv = 1.f / s;
#pragma unroll
        for (int j = 0; j < 10; ++j) out[tid * 10 + j] = lg[j] * inv;
      }
    }
  }
}

// ==================== fallback: proven R13 5-kernel pipeline ================
__global__ __launch_bounds__(256) void conv0_prep_fb(
    const float* __restrict__ in, const float* __restrict__ W0,
    const float* __restrict__ b0, const float* __restrict__ wsh,
    const float* __restrict__ Wd, unsigned short* __restrict__ ws) {
  if (blockIdx.x >= 1024) {
    prep_item((blockIdx.x - 1024) * 256 + threadIdx.x, wsh, Wd, ws);
    return;
  }
  const int wb = swz_bid((int)blockIdx.x, 1024);
  conv0_unit(wb, (int)threadIdx.x, in, W0, b0, ws + A64e);
}

template <int LGS, bool POOL, bool OPAD>
__global__ __launch_bounds__(256, 4) void conv_mfma_fb(
    const unsigned short* __restrict__ act, const float* __restrict__ bsh,
    unsigned short* __restrict__ outp) {
  constexpr int S = 1 << LGS, TC = S >> 4;
  constexpr int NB = (16 * (S >> 1) * TC * 2) / 4;
  const int wb = swz_bid((int)blockIdx.x, NB);
  const int wid = __builtin_amdgcn_readfirstlane((int)(threadIdx.x >> 6));
  const int id = wb * 4 + wid;
  const int l = (int)(threadIdx.x & 63);
  const int n = l & 15, g = l >> 4;
  const int fhalf = id & 1;

  const unsigned short* pA = g_wbf + (fhalf * 16 + n) * 288 + 8 * g;
  bf16x8 af[9];
#pragma unroll
  for (int t = 0; t < 9; ++t) af[t] = *(const bf16x8*)(pA + t * 32);
  const float4 bias = *(const float4*)(bsh + fhalf * 16 + 4 * g);
  const float bv[4] = {bias.x, bias.y, bias.z, bias.w};

  conv_body<LGS, POOL, OPAD>(id, n, g, act, outp, af, bv);
}

__global__ __launch_bounds__(256, 4) void conv4_dense_fb(
    const unsigned short* __restrict__ act, const float* __restrict__ bsh,
    const unsigned short* __restrict__ wd2, const float* __restrict__ bd,
    float* __restrict__ logits, int* __restrict__ cnt,
    float* __restrict__ out) {
  constexpr int PS = 34;
  const int wb = swz_bid((int)blockIdx.x, 256);
  const int wid = __builtin_amdgcn_readfirstlane((int)(threadIdx.x >> 6));
  const int id = wb * 4 + wid;
  const int fhalf = id & 1;
  const int tc = (id >> 1) & 1;
  const int h2 = (id >> 2) & 15;
  const int b = id >> 6;
  const int l = (int)(threadIdx.x & 63);
  const int n = l & 15, g = l >> 4;

  const unsigned short* pA = g_wbf + (fhalf * 16 + n) * 288 + 8 * g;
  bf16x8 af[9];
#pragma unroll
  for (int t = 0; t < 9; ++t) af[t] = *(const bf16x8*)(pA + t * 32);
  const float4 bias = *(const float4*)(bsh + fhalf * 16 + 4 * g);
  const float bv[4] = {bias.x, bias.y, bias.z, bias.w};

  const unsigned short* pB =
      act + ((size_t)(b * PS + 2 * h2) * PS + tc * 16 + n) * 32 + 8 * g;
  bf16x8 bfr[4][3];
#pragma unroll
  for (int rr = 0; rr < 4; ++rr)
#pragma unroll
    for (int dx = 0; dx < 3; ++dx)
      bfr[rr][dx] = *(const bf16x8*)(pB + (rr * PS + dx) * 32);

  f32x4 acc0 = {0.f, 0.f, 0.f, 0.f};
  f32x4 acc1 = {0.f, 0.f, 0.f, 0.f};
#pragma unroll
  for (int tap = 0; tap < 9; ++tap) {
    const int dy = tap / 3, dx = tap - dy * 3;
    acc0 = __builtin_amdgcn_mfma_f32_16x16x32_bf16(af[tap], bfr[dy][dx], acc0, 0, 0, 0);
    acc1 = __builtin_amdgcn_mfma_f32_16x16x32_bf16(af[tap], bfr[dy + 1][dx], acc1, 0, 0, 0);
  }

  float m[4];
#pragma unroll
  for (int r = 0; r < 4; ++r) {
    const float v0 = fmaxf(acc0[r] + bv[r], 0.f);
    const float v1 = fmaxf(acc1[r] + bv[r], 0.f);
    m[r] = fmaxf(v0, v1);
    m[r] = fmaxf(m[r], __shfl_xor(m[r], 1, 64));
  }

  float dacc[10];
#pragma unroll
  for (int j = 0; j < 10; ++j) dacc[j] = 0.f;
  if (!(n & 1)) {
    const int flat0 = ((h2 * 16) + tc * 8 + (n >> 1)) * 32 + fhalf * 16 + 4 * g;
    const unsigned short* wr0 = wd2 + (size_t)flat0 * 16;
#pragma unroll
    for (int r = 0; r < 4; ++r) {
      const unsigned short* wr = wr0 + r * 16;
      const bf16x8 w0 = *(const bf16x8*)wr;
      const unsigned w1 = *(const unsigned*)(wr + 8);
      const float xv = m[r];
#pragma unroll
      for (int j = 0; j < 8; ++j) dacc[j] += xv * bf2f((unsigned short)w0[j]);
      dacc[8] += xv * bf2f((unsigned short)(w1 & 0xffffu));
      dacc[9] += xv * bf2f((unsigned short)(w1 >> 16));
    }
  }
#pragma unroll
  for (int off = 32; off > 0; off >>= 1)
#pragma unroll
    for (int j = 0; j < 10; ++j) dacc[j] += __shfl_xor(dacc[j], off, 64);

  __shared__ float red[4][10];
  __shared__ float sm[160];
  __shared__ int lastflag;
  if (l == 0) {
#pragma unroll
    for (int j = 0; j < 10; ++j) red[wid][j] = dacc[j];
  }
  __syncthreads();
  const int tid = (int)threadIdx.x;
  if (tid < 10) {
    const float s = red[0][tid] + red[1][tid] + red[2][tid] + red[3][tid];
    atomicAdd(logits + b * 10 + tid, s);
    __threadfence();
  }
  __syncthreads();
  if (tid == 0) {
    const int old = atomicAdd(cnt, 1);
    lastflag = (old == 255) ? 1 : 0;
  }
  __syncthreads();

  if (lastflag) {
    if (tid < 160) {
      const int j = tid - (tid / 10) * 10;
      sm[tid] = atomicAdd(logits + tid, 0.f) + bd[j];
    }
    __syncthreads();
    if (tid < 16) {
      float lg[10];
      float mx = -1e30f;
#pragma unroll
      for (int j = 0; j < 10; ++j) {
        lg[j] = sm[tid * 10 + j];
        mx = fmaxf(mx, lg[j]);
      }
      float s = 0.f;
#pragma unroll
      for (int j = 0; j < 10; ++j) {
        lg[j] = expf(lg[j] - mx);
        s += lg[j];
      }
      const float inv = 1.f / s;
#pragma unroll
      for (int j = 0; j < 10; ++j) out[tid * 10 + j] = lg[j] * inv;
    }
  }
}

extern "C" void kernel_launch(void* const* d_in, const int* in_sizes, int n_in,
                              void* d_out, int out_size, void* d_ws, size_t ws_size,
                              hipStream_t stream) {
  const float* in = (const float*)d_in[0];
  const float* W0 = (const float*)d_in[1];
  const float* b0 = (const float*)d_in[2];
  const float* wsh = (const float*)d_in[3];
  const float* bsh = (const float*)d_in[4];
  const float* Wd = (const float*)d_in[5];
  const float* bd = (const float*)d_in[6];
  float* out = (float*)d_out;
  unsigned short* ws = (unsigned short*)d_ws;

  void* args[] = {(void*)&in,  (void*)&W0, (void*)&b0, (void*)&wsh, (void*)&Wd,
                  (void*)&bsh, (void*)&bd, (void*)&ws, (void*)&out};
  hipError_t err = hipLaunchCooperativeKernel((void*)meganet512, dim3(512),
                                              dim3(256), args, 0, stream);
  if (err != hipSuccess) {
    // proven R13 pipeline
    unsigned short* A64 = ws + A64e;
    unsigned short* B64 = ws + B64e;
    unsigned short* A32 = ws + A32e;
    unsigned short* B32 = ws + B32e;
    unsigned short* Wd2 = ws + Dne;
    float* logits = (float*)(ws + LGe);
    int* cnt = (int*)(logits + 160);

    conv0_prep_fb<<<1111, 256, 0, stream>>>(in, W0, b0, wsh, Wd, ws);
    conv_mfma_fb<6, false, false><<<1024, 256, 0, stream>>>(A64, bsh, B64);
    conv_mfma_fb<6, true, true><<<1024, 256, 0, stream>>>(B64, bsh, A32);
    conv_mfma_fb<5, false, false><<<256, 256, 0, stream>>>(A32, bsh, B32);
    conv4_dense_fb<<<256, 256, 0, stream>>>(B32, bsh, Wd2, bd, logits, cnt, out);
  }
}

// Round 17
// 36.994 us; speedup vs baseline: 8.0964x; 8.0964x over previous
//
#include <hip/hip_runtime.h>
#include <math.h>

// Dims: B=16, H=64, W=64, Cin=3, F=32, K=3
// FINAL structure (R13-proven): 5 launches:
//   conv0+prep | conv1 | conv2+pool | conv3 | conv4+pool+dense+softmax.
// Convs 1-4: bf16 MFMA 16x16x32, A=weights(16 filters), B=activations(16 px),
// K=288; PERMUTED channel layout pi (pos 8g+j <-> ch j<4?4g+j:16+4g+j-4) so
// every frag is ONE 16B load; contraction cancels pi (A,B share k-order).
// Activations zero-padded [16][S+2][S+2][32] bf16 -> unconditional halo loads.
// XCD-affinity swizzle in every kernel (image-major work ids; each XCD owns
// 2 images at every layer -> layer k's output is L2-resident for layer k+1).
// conv4 fuses pool + dense partial (Wd2 bf16 [8192][16]) + atomicAdd logits +
// counter/lastflag softmax. Cooperative mega-kernel REJECTED by measurement
// (R16: grid.sync cost ~70us/phase at this working set); low-parallelism
// fusions REJECTED (R10/R11).

typedef __attribute__((ext_vector_type(8))) short bf16x8;
typedef __attribute__((ext_vector_type(4))) float f32x4;

__device__ __align__(16) unsigned short g_wbf[32 * 288];  // bf16 [f][tap*32+pos]
__device__ __align__(64) float g_zerof[16];               // zero page (floats)

// ---- workspace layout (ushort elems) ----
#define A64e ((size_t)0)
#define B64e ((size_t)(16 * 66 * 66 * 32))            // 2,230,272
#define A32e ((size_t)(2 * 16 * 66 * 66 * 32))        // 4,460,544
#define B32e (A32e + (size_t)(16 * 34 * 34 * 32))     // 5,052,416
#define Dne  (B32e + (size_t)(16 * 34 * 34 * 32))     // Wd2 bf16 [8192][16]
#define LGe  (Dne + (size_t)131072)                   // logits f32[160] + cnt

__device__ __forceinline__ unsigned short f2bf(float x) {
  union { float f; unsigned u; } v;
  v.f = x;
  return (unsigned short)((v.u + 0x7FFFu + ((v.u >> 16) & 1u)) >> 16);
}
__device__ __forceinline__ float bf2f(unsigned short x) {
  union { unsigned u; float f; } v;
  v.u = ((unsigned)x) << 16;
  return v.f;
}
__device__ __forceinline__ int swz_bid(int bid, int nwg) {
  return (bid & 7) * (nwg >> 3) + (bid >> 3);
}

// ---- prep item dispatcher ----
__device__ __forceinline__ void prep_item(
    int i, const float* __restrict__ wsh, const float* __restrict__ Wd,
    unsigned short* __restrict__ ws) {
  if (i < 1152) {  // g_wbf convert+permute: one 16B chunk per thread
    const int o0 = i * 8;
    const int f = o0 / 288;
    const int rem = o0 - f * 288;
    const int tap = rem >> 5;
    const int gg = (rem & 31) >> 3;
    unsigned short u[8];
#pragma unroll
    for (int j = 0; j < 8; ++j) {
      const int c = (j < 4) ? 4 * gg + j : 16 + 4 * gg + (j - 4);
      u[j] = f2bf(wsh[f * 288 + tap * 32 + c]);
    }
    uint4 o;
    o.x = u[0] | ((unsigned)u[1] << 16);
    o.y = u[2] | ((unsigned)u[3] << 16);
    o.z = u[4] | ((unsigned)u[5] << 16);
    o.w = u[6] | ((unsigned)u[7] << 16);
    *(uint4*)(g_wbf + o0) = o;
    return;
  }
  i -= 1152;
  if (i < 12544) {  // pad zeroing (one 64B chunk each)
    size_t off;
    if (i < 8320) {
      const size_t base = (i < 4160) ? A64e : B64e;
      if (i >= 4160) i -= 4160;
      if (i < 2112) {
        const int b = i / 132, rem = i - b * 132;
        const int rs = rem / 66, ch = rem - rs * 66;
        off = base + (size_t)((b * 66 + (rs ? 65 : 0)) * 66) * 32 + ch * 32;
      } else {
        i -= 2112;
        const int b = i >> 7, rem = i & 127;
        const int r = rem >> 1, side = rem & 1;
        off = base + (size_t)((b * 66 + 1 + r) * 66 + (side ? 65 : 0)) * 32;
      }
    } else {
      i -= 8320;
      const size_t base = (i < 2112) ? A32e : B32e;
      if (i >= 2112) i -= 2112;
      if (i < 1088) {
        const int b = i / 68, rem = i - b * 68;
        const int rs = rem / 34, ch = rem - rs * 34;
        off = base + (size_t)((b * 34 + (rs ? 33 : 0)) * 34) * 32 + ch * 32;
      } else {
        i -= 1088;
        const int b = i >> 6, rem = i & 63;
        const int r = rem >> 1, side = rem & 1;
        off = base + (size_t)((b * 34 + 1 + r) * 34 + (side ? 33 : 0)) * 32;
      }
    }
    uint4* p = (uint4*)(ws + off);
    const uint4 z = {0u, 0u, 0u, 0u};
    p[0] = z; p[1] = z; p[2] = z; p[3] = z;
    return;
  }
  i -= 12544;
  if (i < 8192) {  // Wd2 [8192][16] bf16, coalesced row transpose
    const int q = i;
    unsigned short u[10];
#pragma unroll
    for (int j = 0; j < 10; ++j) u[j] = f2bf(Wd[(size_t)q * 10 + j]);
    uint4 o0, o1;
    o0.x = u[0] | ((unsigned)u[1] << 16);
    o0.y = u[2] | ((unsigned)u[3] << 16);
    o0.z = u[4] | ((unsigned)u[5] << 16);
    o0.w = u[6] | ((unsigned)u[7] << 16);
    o1.x = u[8] | ((unsigned)u[9] << 16);
    o1.y = 0u; o1.z = 0u; o1.w = 0u;
    *(uint4*)(ws + Dne + (size_t)q * 16) = o0;
    *(uint4*)(ws + Dne + (size_t)q * 16 + 8) = o1;
    return;
  }
  i -= 8192;
  if (i < 161) ((unsigned*)(ws + LGe))[i] = 0u;  // logits[160] + counter
}

// ---- conv0 unit: virtual block v in [0,1024), 256 threads ----
__device__ __forceinline__ void conv0_unit(
    int v, int tid, const float* __restrict__ in, const float* __restrict__ W0,
    const float* __restrict__ b0, unsigned short* __restrict__ A64) {
  const int fg = v & 3;
  const int p = (v >> 2) * 256 + tid;
  const int b = p >> 12, rem = p & 4095, h = rem >> 6, w = rem & 63;

  const float* pt[3][3];
#pragma unroll
  for (int r = 0; r < 3; ++r) {
    const int hh = h - 1 + r;
#pragma unroll
    for (int j = 0; j < 3; ++j) {
      const int col = w - 1 + j;
      const bool ok = ((unsigned)hh < 64u) && ((unsigned)col < 64u);
      pt[r][j] = ok ? in + (((b << 6) + hh) * 64 + col) * 3 : g_zerof;
    }
  }

  float acc[8];
#pragma unroll
  for (int f = 0; f < 8; ++f) acc[f] = b0[fg * 8 + f];  // s_load

#pragma unroll
  for (int dy = 0; dy < 3; ++dy)
#pragma unroll
    for (int dx = 0; dx < 3; ++dx) {
      const float c0 = pt[dy][dx][0];
      const float c1 = pt[dy][dx][1];
      const float c2 = pt[dy][dx][2];
      const float* wp = W0 + ((dy * 3 + dx) * 3) * 32 + fg * 8;  // s_load rows
#pragma unroll
      for (int f = 0; f < 8; ++f)
        acc[f] += c0 * wp[f] + c1 * wp[32 + f] + c2 * wp[64 + f];
    }

  // permuted store: channels fg*8+4q+k -> pos 8*(2*(fg&1)+q) + 4*(fg>>1) + k
  unsigned short* op = A64 + ((size_t)(b * 66 + 1 + h) * 66 + 1 + w) * 32;
  const int hi = fg >> 1;
#pragma unroll
  for (int q = 0; q < 2; ++q) {
    const int pos = 8 * (2 * (fg & 1) + q) + 4 * hi;
    unsigned short u0 = f2bf(fmaxf(acc[4 * q + 0], 0.f));
    unsigned short u1 = f2bf(fmaxf(acc[4 * q + 1], 0.f));
    unsigned short u2 = f2bf(fmaxf(acc[4 * q + 2], 0.f));
    unsigned short u3 = f2bf(fmaxf(acc[4 * q + 3], 0.f));
    uint2 o;
    o.x = u0 | ((unsigned)u1 << 16);
    o.y = u2 | ((unsigned)u3 << 16);
    *(uint2*)(op + pos) = o;
  }
}

// ---- conv body (B-frag load + 18 MFMA + epilogue); af/bv preloaded ----
template <int LGS, bool POOL>
__device__ __forceinline__ void conv_body(
    int id, int n, int g, const unsigned short* __restrict__ act,
    unsigned short* __restrict__ outp, const bf16x8 (&af)[9],
    const float (&bv)[4]) {
  constexpr int S = 1 << LGS, PS = S + 2, LGTC = LGS - 4, TC = S >> 4;
  const int fhalf = id & 1;
  const int tc = (id >> 1) & (TC - 1);
  const int h2 = (id >> (1 + LGTC)) & ((S >> 1) - 1);
  const int b = id >> (LGS + LGTC);

  const unsigned short* pB =
      act + ((size_t)(b * PS + 2 * h2) * PS + tc * 16 + n) * 32 + 8 * g;
  bf16x8 bfr[4][3];
#pragma unroll
  for (int rr = 0; rr < 4; ++rr)
#pragma unroll
    for (int dx = 0; dx < 3; ++dx)
      bfr[rr][dx] = *(const bf16x8*)(pB + (rr * PS + dx) * 32);

  f32x4 acc0 = {0.f, 0.f, 0.f, 0.f};
  f32x4 acc1 = {0.f, 0.f, 0.f, 0.f};
#pragma unroll
  for (int tap = 0; tap < 9; ++tap) {
    const int dy = tap / 3, dx = tap - dy * 3;
    acc0 = __builtin_amdgcn_mfma_f32_16x16x32_bf16(af[tap], bfr[dy][dx], acc0, 0, 0, 0);
    acc1 = __builtin_amdgcn_mfma_f32_16x16x32_bf16(af[tap], bfr[dy + 1][dx], acc1, 0, 0, 0);
  }

  const int opos = 8 * g + 4 * fhalf;
  if (!POOL) {
#pragma unroll
    for (int t = 0; t < 2; ++t) {
      unsigned short u[4];
#pragma unroll
      for (int r = 0; r < 4; ++r) {
        const float a = (t == 0) ? acc0[r] : acc1[r];
        u[r] = f2bf(fmaxf(a + bv[r], 0.f));
      }
      uint2 o;
      o.x = u[0] | ((unsigned)u[1] << 16);
      o.y = u[2] | ((unsigned)u[3] << 16);
      unsigned short* op = outp +
          ((size_t)(b * PS + 2 * h2 + 1 + t) * PS + 1 + tc * 16 + n) * 32 + opos;
      *(uint2*)op = o;
    }
  } else {
    float m[4];
#pragma unroll
    for (int r = 0; r < 4; ++r) {
      const float v0 = fmaxf(acc0[r] + bv[r], 0.f);
      const float v1 = fmaxf(acc1[r] + bv[r], 0.f);
      m[r] = fmaxf(v0, v1);
      m[r] = fmaxf(m[r], __shfl_xor(m[r], 1, 64));
    }
    if (!(n & 1)) {
      unsigned short u[4];
#pragma unroll
      for (int r = 0; r < 4; ++r) u[r] = f2bf(m[r]);
      uint2 o;
      o.x = u[0] | ((unsigned)u[1] << 16);
      o.y = u[2] | ((unsigned)u[3] << 16);
      unsigned short* op =
          outp + ((size_t)(b * 34 + 1 + h2) * 34 + 1 + tc * 8 + (n >> 1)) * 32 + opos;
      *(uint2*)op = o;
    }
  }
}

// ==================== kernel 1: prep + conv0 ================================
__global__ __launch_bounds__(256) void conv0_prep(
    const float* __restrict__ in, const float* __restrict__ W0,
    const float* __restrict__ b0, const float* __restrict__ wsh,
    const float* __restrict__ Wd, unsigned short* __restrict__ ws) {
  if (blockIdx.x >= 1024) {
    prep_item((blockIdx.x - 1024) * 256 + threadIdx.x, wsh, Wd, ws);
    return;
  }
  const int wb = swz_bid((int)blockIdx.x, 1024);
  conv0_unit(wb, (int)threadIdx.x, in, W0, b0, ws + A64e);
}

// ==================== kernels 2-4: MFMA convs ===============================
template <int LGS, bool POOL>
__global__ __launch_bounds__(256, 4) void conv_mfma(
    const unsigned short* __restrict__ act, const float* __restrict__ bsh,
    unsigned short* __restrict__ outp) {
  constexpr int S = 1 << LGS, TC = S >> 4;
  constexpr int NB = (16 * (S >> 1) * TC * 2) / 4;
  const int wb = swz_bid((int)blockIdx.x, NB);
  const int wid = __builtin_amdgcn_readfirstlane((int)(threadIdx.x >> 6));
  const int id = wb * 4 + wid;
  const int l = (int)(threadIdx.x & 63);
  const int n = l & 15, g = l >> 4;
  const int fhalf = id & 1;

  const unsigned short* pA = g_wbf + (fhalf * 16 + n) * 288 + 8 * g;
  bf16x8 af[9];
#pragma unroll
  for (int t = 0; t < 9; ++t) af[t] = *(const bf16x8*)(pA + t * 32);
  const float4 bias = *(const float4*)(bsh + fhalf * 16 + 4 * g);
  const float bv[4] = {bias.x, bias.y, bias.z, bias.w};

  conv_body<LGS, POOL>(id, n, g, act, outp, af, bv);
}

// ==================== kernel 5: conv4 + pool + dense + softmax ==============
__global__ __launch_bounds__(256, 4) void conv4_dense(
    const unsigned short* __restrict__ act, const float* __restrict__ bsh,
    const unsigned short* __restrict__ wd2, const float* __restrict__ bd,
    float* __restrict__ logits, int* __restrict__ cnt,
    float* __restrict__ out) {
  constexpr int PS = 34;
  const int wb = swz_bid((int)blockIdx.x, 256);
  const int wid = __builtin_amdgcn_readfirstlane((int)(threadIdx.x >> 6));
  const int id = wb * 4 + wid;
  const int fhalf = id & 1;
  const int tc = (id >> 1) & 1;
  const int h2 = (id >> 2) & 15;
  const int b = id >> 6;
  const int l = (int)(threadIdx.x & 63);
  const int n = l & 15, g = l >> 4;

  const unsigned short* pA = g_wbf + (fhalf * 16 + n) * 288 + 8 * g;
  bf16x8 af[9];
#pragma unroll
  for (int t = 0; t < 9; ++t) af[t] = *(const bf16x8*)(pA + t * 32);
  const float4 bias = *(const float4*)(bsh + fhalf * 16 + 4 * g);
  const float bv[4] = {bias.x, bias.y, bias.z, bias.w};

  const unsigned short* pB =
      act + ((size_t)(b * PS + 2 * h2) * PS + tc * 16 + n) * 32 + 8 * g;
  bf16x8 bfr[4][3];
#pragma unroll
  for (int rr = 0; rr < 4; ++rr)
#pragma unroll
    for (int dx = 0; dx < 3; ++dx)
      bfr[rr][dx] = *(const bf16x8*)(pB + (rr * PS + dx) * 32);

  f32x4 acc0 = {0.f, 0.f, 0.f, 0.f};
  f32x4 acc1 = {0.f, 0.f, 0.f, 0.f};
#pragma unroll
  for (int tap = 0; tap < 9; ++tap) {
    const int dy = tap / 3, dx = tap - dy * 3;
    acc0 = __builtin_amdgcn_mfma_f32_16x16x32_bf16(af[tap], bfr[dy][dx], acc0, 0, 0, 0);
    acc1 = __builtin_amdgcn_mfma_f32_16x16x32_bf16(af[tap], bfr[dy + 1][dx], acc1, 0, 0, 0);
  }

  float m[4];
#pragma unroll
  for (int r = 0; r < 4; ++r) {
    const float v0 = fmaxf(acc0[r] + bv[r], 0.f);
    const float v1 = fmaxf(acc1[r] + bv[r], 0.f);
    m[r] = fmaxf(v0, v1);
    m[r] = fmaxf(m[r], __shfl_xor(m[r], 1, 64));
  }

  // dense partial: even lanes own pooled px (h2, tc*8+n/2), ch fhalf*16+4g..+3
  float dacc[10];
#pragma unroll
  for (int j = 0; j < 10; ++j) dacc[j] = 0.f;
  if (!(n & 1)) {
    const int flat0 = ((h2 * 16) + tc * 8 + (n >> 1)) * 32 + fhalf * 16 + 4 * g;
    const unsigned short* wr0 = wd2 + (size_t)flat0 * 16;
#pragma unroll
    for (int r = 0; r < 4; ++r) {
      const unsigned short* wr = wr0 + r * 16;
      const bf16x8 w0 = *(const bf16x8*)wr;            // j 0..7
      const unsigned w1 = *(const unsigned*)(wr + 8);  // j 8..9
      const float xv = m[r];
#pragma unroll
      for (int j = 0; j < 8; ++j) dacc[j] += xv * bf2f((unsigned short)w0[j]);
      dacc[8] += xv * bf2f((unsigned short)(w1 & 0xffffu));
      dacc[9] += xv * bf2f((unsigned short)(w1 >> 16));
    }
  }
#pragma unroll
  for (int off = 32; off > 0; off >>= 1)
#pragma unroll
    for (int j = 0; j < 10; ++j) dacc[j] += __shfl_xor(dacc[j], off, 64);

  __shared__ float red[4][10];
  __shared__ float sm[160];
  __shared__ int lastflag;
  if (l == 0) {
#pragma unroll
    for (int j = 0; j < 10; ++j) red[wid][j] = dacc[j];
  }
  __syncthreads();
  const int tid = (int)threadIdx.x;
  if (tid < 10) {
    const float s = red[0][tid] + red[1][tid] + red[2][tid] + red[3][tid];
    atomicAdd(logits + b * 10 + tid, s);
    __threadfence();
  }
  __syncthreads();
  if (tid == 0) {
    const int old = atomicAdd(cnt, 1);
    lastflag = (old == 255) ? 1 : 0;
  }
  __syncthreads();

  if (lastflag) {
    if (tid < 160) {
      const int j = tid - (tid / 10) * 10;
      sm[tid] = atomicAdd(logits + tid, 0.f) + bd[j];
    }
    __syncthreads();
    if (tid < 16) {
      float lg[10];
      float mx = -1e30f;
#pragma unroll
      for (int j = 0; j < 10; ++j) {
        lg[j] = sm[tid * 10 + j];
        mx = fmaxf(mx, lg[j]);
      }
      float s = 0.f;
#pragma unroll
      for (int j = 0; j < 10; ++j) {
        lg[j] = expf(lg[j] - mx);
        s += lg[j];
      }
      const float inv = 1.f / s;
#pragma unroll
      for (int j = 0; j < 10; ++j) out[tid * 10 + j] = lg[j] * inv;
    }
  }
}

extern "C" void kernel_launch(void* const* d_in, const int* in_sizes, int n_in,
                              void* d_out, int out_size, void* d_ws, size_t ws_size,
                              hipStream_t stream) {
  const float* in = (const float*)d_in[0];
  const float* W0 = (const float*)d_in[1];
  const float* b0 = (const float*)d_in[2];
  const float* wsh = (const float*)d_in[3];
  const float* bsh = (const float*)d_in[4];
  const float* Wd = (const float*)d_in[5];
  const float* bd = (const float*)d_in[6];
  float* out = (float*)d_out;
  unsigned short* ws = (unsigned short*)d_ws;

  unsigned short* A64 = ws + A64e;
  unsigned short* B64 = ws + B64e;
  unsigned short* A32 = ws + A32e;
  unsigned short* B32 = ws + B32e;
  unsigned short* Wd2 = ws + Dne;
  float* logits = (float*)(ws + LGe);
  int* cnt = (int*)(logits + 160);

  conv0_prep<<<1111, 256, 0, stream>>>(in, W0, b0, wsh, Wd, ws);
  conv_mfma<6, false><<<1024, 256, 0, stream>>>(A64, bsh, B64);  // conv1
  conv_mfma<6, true><<<1024, 256, 0, stream>>>(B64, bsh, A32);   // conv2+pool
  conv_mfma<5, false><<<256, 256, 0, stream>>>(A32, bsh, B32);   // conv3
  conv4_dense<<<256, 256, 0, stream>>>(B32, bsh, Wd2, bd, logits, cnt, out);
}